// Round 7
// baseline (589.362 us; speedup 1.0000x reference)
//
#include <hip/hip_runtime.h>

#define NN 100000
#define NE 1600000
#define NG 64
#define DI 128
#define DH 256
#define DO 128
#define NBUK 8
#define BUKSZ 12500   // NN / NBUK

using short8 = __attribute__((ext_vector_type(8))) short;
using f32x4  = __attribute__((ext_vector_type(4))) float;

__device__ __forceinline__ float bf2f(unsigned short u) {
    return __uint_as_float(((unsigned)u) << 16);
}
__device__ __forceinline__ unsigned short f2bf(float f) {
    unsigned u = __float_as_uint(f);
    unsigned r = (u + 0x7FFFu + ((u >> 16) & 1u)) >> 16;   // RNE
    return (unsigned short)r;
}

// ---------------- small utility kernels ----------------

__global__ void k_zero(float* p, int n) {
    int i = blockIdx.x * blockDim.x + threadIdx.x;
    if (i < n) p[i] = 0.0f;
}
__global__ void k_zero_int(int* p, int n) {
    int i = blockIdx.x * blockDim.x + threadIdx.x;
    if (i < n) p[i] = 0;
}

// per-(dst, src-bucket) histogram
__global__ void k_hist2(const int* __restrict__ src, const int* __restrict__ dst,
                        int* __restrict__ cnt2, int e) {
    int i = blockIdx.x * blockDim.x + threadIdx.x;
    if (i < e) {
        int b = src[i] / BUKSZ;
        atomicAdd(&cnt2[dst[i] * NBUK + b], 1);
    }
}

// f32 -> bf16 bulk convert (4 elems/thread)
__global__ void k_cvt_bf(const float* __restrict__ in, unsigned short* __restrict__ out, int n4) {
    int i = blockIdx.x * blockDim.x + threadIdx.x;
    if (i >= n4) return;
    float4 v = ((const float4*)in)[i];
    ushort4 o;
    o.x = f2bf(v.x); o.y = f2bf(v.y); o.z = f2bf(v.z); o.w = f2bf(v.w);
    ((ushort4*)out)[i] = o;
}

// W (KxN f32, row-major) -> Wt (NxK bf16)
__global__ void k_wt(const float* __restrict__ W, unsigned short* __restrict__ Wt, int K, int N) {
    int i = blockIdx.x * blockDim.x + threadIdx.x;
    if (i >= K * N) return;
    int k = i / N, n = i % N;
    Wt[n * K + k] = f2bf(W[i]);
}

// ---------------- scan: per-node degree = sum of 8 bucket counts ----------------

__global__ void k_scan1b(const int* __restrict__ cnt2, int* __restrict__ tmp,
                         int* __restrict__ bsum, int n) {
    __shared__ int sh[256];
    int t = threadIdx.x;
    int i = blockIdx.x * 256 + t;
    int v = 0;
    if (i < n) {
        int4 a = ((const int4*)cnt2)[i * 2];
        int4 b = ((const int4*)cnt2)[i * 2 + 1];
        v = a.x + a.y + a.z + a.w + b.x + b.y + b.z + b.w;
    }
    sh[t] = v;
    __syncthreads();
    for (int off = 1; off < 256; off <<= 1) {
        int add = (t >= off) ? sh[t - off] : 0;
        __syncthreads();
        sh[t] += add;
        __syncthreads();
    }
    if (i < n) tmp[i] = sh[t] - v;
    if (t == 255) bsum[blockIdx.x] = sh[255];
}
__global__ void k_scan2(int* __restrict__ bsum, int nb) {
    __shared__ int sh[512];
    int t = threadIdx.x;
    int v = (t < nb) ? bsum[t] : 0;
    sh[t] = v;
    __syncthreads();
    for (int off = 1; off < 512; off <<= 1) {
        int add = (t >= off) ? sh[t - off] : 0;
        __syncthreads();
        sh[t] += add;
        __syncthreads();
    }
    if (t < nb) bsum[t] = sh[t] - v;
}
// finalize: rs2 (per-node,bucket row pointers), cursor init (in cnt2), dinv
__global__ void k_fin(const int* __restrict__ tmp, const int* __restrict__ bsum,
                      int* __restrict__ cnt2, int* __restrict__ rs2,
                      float* __restrict__ dinv, int n, int total) {
    int i = blockIdx.x * 256 + threadIdx.x;
    if (i < n) {
        int base = tmp[i] + bsum[blockIdx.x];
        int c[NBUK];
#pragma unroll
        for (int b = 0; b < NBUK; ++b) c[b] = cnt2[i * NBUK + b];
        int pos = base;
#pragma unroll
        for (int b = 0; b < NBUK; ++b) {
            rs2[i * NBUK + b] = pos;
            cnt2[i * NBUK + b] = pos;   // becomes fill cursor
            pos += c[b];
        }
        dinv[i] = rsqrtf((float)(pos - base + 1));
    }
    if (i == 0) rs2[n * NBUK] = total;
}

// ---------------- CSR fill: dst-range passes, per-(dst,bucket) cursor ----------------

__global__ void k_fill_csr(const int* __restrict__ src, const int* __restrict__ dst,
                           int* __restrict__ cur2, int* __restrict__ csr_src,
                           int e, int lo, int hi) {
    int i = blockIdx.x * blockDim.x + threadIdx.x;
    if (i < e) {
        int d = dst[i];
        if (d >= lo && d < hi) {
            int s = src[i];
            int pos = atomicAdd(&cur2[d * NBUK + s / BUKSZ], 1);
            csr_src[pos] = s;
        }
    }
}

// ---------------- bucket-outer aggregation: out = A_hat @ feat (D=128) ----------------
// 32-lane groups, 8 nodes/group, acc held across src-bucket loop.
// POOL=false: write bf16 rows. POOL=true: fused global_add_pool (f32 atomics).
template<bool POOL>
__global__ __launch_bounds__(256) void k_aggb(const unsigned short* __restrict__ feat,
        const int* __restrict__ csr_src, const int* __restrict__ rs2,
        const float* __restrict__ dinv, const int* __restrict__ batch,
        void* __restrict__ outv, float* __restrict__ cnt, int n) {
    const int R = 8;
    int group = blockIdx.x * 8 + (threadIdx.x >> 5);
    int lane = threadIdx.x & 31;
    int start = group * R;
    if (start >= n) return;
    const ushort4* f4 = (const ushort4*)feat;

    float4 acc[R];
#pragma unroll
    for (int r = 0; r < R; ++r) acc[r] = make_float4(0.f, 0.f, 0.f, 0.f);

    for (int b = 0; b < NBUK; ++b) {
#pragma unroll
        for (int r = 0; r < R; ++r) {
            int v = start + r;
            if (v >= n) break;
            int jj = rs2[v * NBUK + b];
            int je = rs2[v * NBUK + b + 1];   // contiguous: valid across node boundary
            for (; jj + 1 < je; jj += 2) {
                int s0 = csr_src[jj], s1 = csr_src[jj + 1];
                float w0 = dinv[s0], w1 = dinv[s1];
                ushort4 u0 = f4[(size_t)s0 * 32 + lane];
                ushort4 u1 = f4[(size_t)s1 * 32 + lane];
                acc[r].x += w0 * bf2f(u0.x) + w1 * bf2f(u1.x);
                acc[r].y += w0 * bf2f(u0.y) + w1 * bf2f(u1.y);
                acc[r].z += w0 * bf2f(u0.z) + w1 * bf2f(u1.z);
                acc[r].w += w0 * bf2f(u0.w) + w1 * bf2f(u1.w);
            }
            if (jj < je) {
                int s = csr_src[jj];
                float w = dinv[s];
                ushort4 u = f4[(size_t)s * 32 + lane];
                acc[r].x += w * bf2f(u.x); acc[r].y += w * bf2f(u.y);
                acc[r].z += w * bf2f(u.z); acc[r].w += w * bf2f(u.w);
            }
        }
    }

    if (!POOL) {
        unsigned short* out = (unsigned short*)outv;
#pragma unroll
        for (int r = 0; r < R; ++r) {
            int v = start + r;
            if (v >= n) break;
            float wd = dinv[v];
            ushort4 a = f4[(size_t)v * 32 + lane];
            ushort4 o;
            o.x = f2bf(wd * (acc[r].x + wd * bf2f(a.x)));
            o.y = f2bf(wd * (acc[r].y + wd * bf2f(a.y)));
            o.z = f2bf(wd * (acc[r].z + wd * bf2f(a.z)));
            o.w = f2bf(wd * (acc[r].w + wd * bf2f(a.w)));
            ((ushort4*)out)[(size_t)v * 32 + lane] = o;
        }
    } else {
        float* out = (float*)outv;
        float4 pacc = make_float4(0.f, 0.f, 0.f, 0.f);
        int curg = batch[start];
        int run = 0;
#pragma unroll
        for (int r = 0; r < R; ++r) {
            int v = start + r;
            if (v >= n) break;
            int gv = batch[v];
            if (gv != curg) {
                float* o = out + curg * 128 + lane * 4;
                atomicAdd(o + 0, pacc.x); atomicAdd(o + 1, pacc.y);
                atomicAdd(o + 2, pacc.z); atomicAdd(o + 3, pacc.w);
                if (lane == 0) atomicAdd(&cnt[curg], (float)run);
                pacc = make_float4(0.f, 0.f, 0.f, 0.f);
                run = 0; curg = gv;
            }
            float wd = dinv[v];
            ushort4 a = f4[(size_t)v * 32 + lane];
            pacc.x += wd * (acc[r].x + wd * bf2f(a.x));
            pacc.y += wd * (acc[r].y + wd * bf2f(a.y));
            pacc.z += wd * (acc[r].z + wd * bf2f(a.z));
            pacc.w += wd * (acc[r].w + wd * bf2f(a.w));
            run++;
        }
        float* o = out + curg * 128 + lane * 4;
        atomicAdd(o + 0, pacc.x); atomicAdd(o + 1, pacc.y);
        atomicAdd(o + 2, pacc.z); atomicAdd(o + 3, pacc.w);
        if (lane == 0) atomicAdd(&cnt[curg], (float)run);
    }
}

// ---------------- bf16 MFMA GEMM: C = act(A @ Bt^T + bias), BM=128, 512 thr ----------------
template<int K, int N, bool RELU, bool BIAS>
__global__ __launch_bounds__(512) void k_gemm_bf(const unsigned short* __restrict__ A,
        const unsigned short* __restrict__ Bt, const float* __restrict__ bias,
        unsigned short* __restrict__ C, int M) {
    constexpr int BM = 128;
    __shared__ unsigned short As[BM * K];   // XOR-swizzled rows
    __shared__ unsigned short Bs[N * K];

    const int tid = threadIdx.x;
    const int bm = blockIdx.x * BM;

    constexpr int AC = BM * K / 8;
    for (int c = tid; c < AC; c += 512) {
        int row = c / (K / 8);
        int kc  = (c % (K / 8)) * 8;
        uint4 v = make_uint4(0, 0, 0, 0);
        int gr = bm + row;
        if (gr < M) v = *(const uint4*)(A + (size_t)gr * K + kc);
        int byte = row * (2 * K) + ((kc * 2) ^ ((row & 7) << 4));
        *(uint4*)((char*)As + byte) = v;
    }
    constexpr int BC = N * K / 8;
    for (int c = tid; c < BC; c += 512) {
        int col = c / (K / 8);
        int kc  = (c % (K / 8)) * 8;
        uint4 v = *(const uint4*)(Bt + (size_t)col * K + kc);
        int byte = col * (2 * K) + ((kc * 2) ^ ((col & 7) << 4));
        *(uint4*)((char*)Bs + byte) = v;
    }
    __syncthreads();

    const int w  = tid >> 6;
    const int l  = tid & 63;
    const int lr = l & 15;
    const int lg = l >> 4;
    const int r0 = w * 16;

    constexpr int NT = N / 16;
    f32x4 acc[NT] = {};

    const int arow  = r0 + lr;
    const int abase = arow * (2 * K);
    const int aswz  = (arow & 7) << 4;

#pragma unroll
    for (int ks = 0; ks < K / 32; ++ks) {
        int kb = ks * 64 + lg * 16;
        short8 a = *(const short8*)((const char*)As + abase + (kb ^ aswz));
#pragma unroll
        for (int n = 0; n < NT; ++n) {
            int col = n * 16 + lr;
            short8 b = *(const short8*)((const char*)Bs + col * (2 * K) + (kb ^ ((col & 7) << 4)));
            acc[n] = __builtin_amdgcn_mfma_f32_16x16x32_bf16(a, b, acc[n], 0, 0, 0);
        }
    }

#pragma unroll
    for (int n = 0; n < NT; ++n) {
        int col = n * 16 + lr;
        float bb = BIAS ? bias[col] : 0.0f;
#pragma unroll
        for (int r = 0; r < 4; ++r) {
            int row = bm + r0 + lg * 4 + r;
            if (row < M) {
                float v = acc[n][r] + bb;
                if (RELU) v = fmaxf(v, 0.f);
                C[(size_t)row * N + col] = f2bf(v);
            }
        }
    }
}

__global__ void k_biasfix(const float* __restrict__ bias, const float* __restrict__ cnt,
                          float* __restrict__ out) {
    int idx = blockIdx.x * blockDim.x + threadIdx.x;
    if (idx >= NG * 128) return;
    int g = idx >> 7, c = idx & 127;
    out[idx] += bias[c] * cnt[g];
}

// ---------------- launch ----------------

extern "C" void kernel_launch(void* const* d_in, const int* in_sizes, int n_in,
                              void* d_out, int out_size, void* d_ws, size_t ws_size,
                              hipStream_t stream) {
    const float* x     = (const float*)d_in[0];
    const int*   ei    = (const int*)d_in[1];
    const int*   batch = (const int*)d_in[2];
    const float* W1    = (const float*)d_in[3];
    const float* b1    = (const float*)d_in[4];
    const float* W2    = (const float*)d_in[5];
    const float* b2    = (const float*)d_in[6];
    float* out = (float*)d_out;

    const int* src = ei;
    const int* dst = ei + NE;

    // workspace layout (16B aligned), ~142.3 MB
    char* ws = (char*)d_ws;
    float*          dinv = (float*)(ws + 0);                    // 400 KB (pad 512K)
    int*            cnt2 = (int*)(ws + 524288);                 // 3.2 MB (reused as cursor)
    int*            rs2  = (int*)(ws + 3879936);                // 3.2 MB + 4
    int*            tmp  = (int*)(ws + 7235584);                // 400 KB
    int*            bsum = (int*)(ws + 7759872);                // 2 KB
    float*          cnt  = (float*)(ws + 7761920);              // 256 B
    unsigned short* w1t  = (unsigned short*)(ws + 7762176);     // 64 KB
    unsigned short* w2t  = (unsigned short*)(ws + 7827712);     // 64 KB
    int*            csr  = (int*)(ws + 7893248);                // 6.4 MB
    unsigned short* xbf  = (unsigned short*)(ws + 14293248);    // 25.6 MB
    unsigned short* agg1 = (unsigned short*)(ws + 39893248);    // 25.6 MB
    unsigned short* h1   = (unsigned short*)(ws + 65493248);    // 51.2 MB
    unsigned short* tbf  = (unsigned short*)(ws + 116693248);   // 25.6 MB

    const int BLK = 256;
    auto cdiv = [](int a, int b) { return (a + b - 1) / b; };
    const int NB = cdiv(NN, 256);   // 391 scan blocks

    // ---- conversions ----
    k_cvt_bf<<<cdiv(NN * 32, BLK), BLK, 0, stream>>>(x, xbf, NN * 32);
    k_wt<<<cdiv(DI * DH, BLK), BLK, 0, stream>>>(W1, w1t, DI, DH);
    k_wt<<<cdiv(DH * DO, BLK), BLK, 0, stream>>>(W2, w2t, DH, DO);

    // ---- bucketed CSR build ----
    k_zero_int<<<cdiv(NN * NBUK, BLK), BLK, 0, stream>>>(cnt2, NN * NBUK);
    k_hist2<<<cdiv(NE, BLK), BLK, 0, stream>>>(src, dst, cnt2, NE);
    k_scan1b<<<NB, 256, 0, stream>>>(cnt2, tmp, bsum, NN);
    k_scan2<<<1, 512, 0, stream>>>(bsum, NB);
    k_fin<<<NB, 256, 0, stream>>>(tmp, bsum, cnt2, rs2, dinv, NN, NE);
    {
        const int NPASS = 4, NPP = (NN + NPASS - 1) / NPASS;
        for (int p = 0; p < NPASS; ++p)
            k_fill_csr<<<cdiv(NE, BLK), BLK, 0, stream>>>(src, dst, cnt2, csr, NE,
                                                          p * NPP, (p + 1) * NPP);
    }

    const int AGG_BLOCKS = cdiv(cdiv(NN, 8), 8);   // 8 nodes/group, 8 groups/block

    // ---- layer 1: agg1 = A_hat @ x ; h1 = relu(agg1 @ W1 + b1) ----
    k_aggb<false><<<AGG_BLOCKS, 256, 0, stream>>>(xbf, csr, rs2, dinv, nullptr, agg1, nullptr, NN);
    k_gemm_bf<DI, DH, true, true><<<cdiv(NN, 128), 512, 0, stream>>>(agg1, w1t, b1, h1, NN);

    // ---- layer 2: t = h1 @ W2 ; fused agg2 + pool ----
    k_gemm_bf<DH, DO, false, false><<<cdiv(NN, 128), 512, 0, stream>>>(h1, w2t, nullptr, tbf, NN);
    k_zero<<<cdiv(NG * 128, BLK), BLK, 0, stream>>>(out, NG * 128);
    k_zero<<<1, 64, 0, stream>>>(cnt, NG);
    k_aggb<true><<<AGG_BLOCKS, 256, 0, stream>>>(tbf, csr, rs2, dinv, batch, out, cnt, NN);
    k_biasfix<<<cdiv(NG * 128, BLK), BLK, 0, stream>>>(b2, cnt, out);
}